// Round 1
// baseline (1498.639 us; speedup 1.0000x reference)
//
#include <hip/hip_runtime.h>
#include <stdint.h>

// ResonanceLayer: routed einsum -> resonance irfft/OLA -> unit-norm ->
// upsample*threefry-noise -> 65536-pt FFT convolution (1024 pairs) ->
// softmax-deformation mix -> tanh(gain*x) summed over resonators.
//
// FFT scheme: radix-2 DIF forward (natural->bitrev), DIT inverse
// (bitrev->natural). Spectra kept in bitrev order; pointwise products are
// order-consistent so no bit-reversal is ever performed.
// 65536 = comb stages (h=32768..256, indices == c mod 256) + block stages
// (h=128..1, contiguous 256-blocks). Each stage-group is LDS-resident.

#define PI_F     3.14159265358979323846f
#define TWOPI_F  6.28318530717958647692f
#define UNIT64K  (TWOPI_F/65536.0f)
#define UNIT2K   (TWOPI_F/2048.0f)

__device__ __forceinline__ float2 cmul(float2 a, float2 b){
  return make_float2(a.x*b.x - a.y*b.y, a.x*b.y + a.y*b.x);
}

// exp(sign * i * e * unit)
__device__ __forceinline__ float2 twid(uint32_t e, float unit, float sign){
  float ang = (float)e * unit;
  float sn, cn;
  __sincosf(ang, &sn, &cn);
  return make_float2(cn, sign*sn);
}

__device__ __forceinline__ uint32_t rotl32(uint32_t v, int r){
  return (v << r) | (v >> (32 - r));
}

// Threefry-2x32, key = (0, 123)  [jax.random.key(123)]
__device__ __forceinline__ void threefry2x32(uint32_t c0, uint32_t c1,
                                             uint32_t& o0, uint32_t& o1){
  const uint32_t k0 = 0u, k1 = 123u;
  const uint32_t k2 = 0x1BD11BDAu ^ k0 ^ k1;
  const uint32_t ks[3] = {k0, k1, k2};
  uint32_t x0 = c0 + k0, x1 = c1 + k1;
#pragma unroll
  for (int i = 0; i < 5; i++){
    if ((i & 1) == 0){
      x0 += x1; x1 = rotl32(x1,13); x1 ^= x0;
      x0 += x1; x1 = rotl32(x1,15); x1 ^= x0;
      x0 += x1; x1 = rotl32(x1,26); x1 ^= x0;
      x0 += x1; x1 = rotl32(x1, 6); x1 ^= x0;
    } else {
      x0 += x1; x1 = rotl32(x1,17); x1 ^= x0;
      x0 += x1; x1 = rotl32(x1,29); x1 ^= x0;
      x0 += x1; x1 = rotl32(x1,16); x1 ^= x0;
      x0 += x1; x1 = rotl32(x1,24); x1 ^= x0;
    }
    x0 += ks[(i+1)%3];
    x1 += ks[(i+2)%3] + (uint32_t)(i+1);
  }
  o0 = x0; o1 = x1;
}

// jax partitionable uniform(-1,1) at flat index p (counter hi=0, lo=p, XOR fold)
__device__ __forceinline__ float jax_noise(uint32_t p){
  uint32_t b0, b1;
  threefry2x32(0u, p, b0, b1);
  uint32_t bits = b0 ^ b1;
  float u = __uint_as_float((bits >> 9) | 0x3f800000u) - 1.0f;
  return fmaxf(-1.0f, u*2.0f - 1.0f);
}

// reference interpolate_last_axis positions: exact in fp32 (scale 2^-8)
__device__ __forceinline__ void interp128(int t, int& lo, int& hi, float& w){
  float posf = ((float)t + 0.5f) * (1.0f/256.0f) - 0.5f;
  posf = fminf(fmaxf(posf, 0.0f), 127.0f);
  lo = (int)posf;
  hi = lo + 1; if (hi > 127) hi = 127;
  w = posf - (float)lo;
}

// ---------------- routed einsum + output1 + softmax(deformations) ----------
__global__ void k_routed(const float* __restrict__ ctrl, const float* __restrict__ defm,
                         const float* __restrict__ router,
                         float* __restrict__ w_routed, float* __restrict__ w_sm,
                         float* __restrict__ out1){
  int idx = blockIdx.x*blockDim.x + threadIdx.x;
  if (idx < 32768){
    int f = idx & 127, r = (idx >> 7) & 31, be = idx >> 12;
    float acc = 0.0f;
#pragma unroll
    for (int c = 0; c < 16; c++)
      acc += ctrl[(be*16 + c)*128 + f] * router[c*32 + r];
    w_routed[idx] = acc;
    out1[idx] = acc;
  } else if (idx < 32768 + 1024){
    int j = idx - 32768;
    int f = j & 127, be = j >> 7;
    float v[4];
#pragma unroll
    for (int x = 0; x < 4; x++)
      v[x] = defm[(be*4 + x)*128 + f] + (x == 0 ? 1.0f : 0.0f);
    float mx = fmaxf(fmaxf(v[0], v[1]), fmaxf(v[2], v[3]));
    float s = 0.0f;
#pragma unroll
    for (int x = 0; x < 4; x++){ v[x] = expf(v[x] - mx); s += v[x]; }
#pragma unroll
    for (int x = 0; x < 4; x++) w_sm[(be*4 + x)*128 + f] = v[x]/s;
  }
}

// -------- resonance frames: irfft(2048) + hann + overlap-add (atomic) ------
__global__ void k_frames(const float* __restrict__ amp, const float* __restrict__ phase,
                         const float* __restrict__ decay, float* __restrict__ w_res){
  const int wg = blockIdx.x;          // (r,x,f)
  const int f = wg & 31;
  const int x = (wg >> 5) & 3;
  const int r = wg >> 7;
  const int t = threadIdx.x;
  __shared__ float2 buf[2048];

  // build full Hermitian spectrum at bit-reversed positions (DC/Nyquist imag
  // dropped, matching pocketfft c2r semantics)
  for (int k = t; k <= 1024; k += 256){
    const int base = (r*1025 + k)*4 + x;
    float a  = fabsf(amp[base]);
    float ph = tanhf(phase[base]) * PI_F;
    float sg = 1.0f / (1.0f + expf(-decay[base]));
    float dc = 0.5f + 0.45f * sg;                    // BASE + sigmoid*SPAN*FACTOR
    float mag = expf(logf(dc + 1e-12f) * (float)(f+1)) * a;
    float snv, csv;
    sincosf(ph, &snv, &csv);
    float re = mag * csv, im = mag * snv;
    if (k == 0 || k == 1024) im = 0.0f;
    buf[__brev((uint32_t)k) >> 21] = make_float2(re, im);
    if (k >= 1 && k <= 1023)
      buf[__brev((uint32_t)(2048 - k)) >> 21] = make_float2(re, -im);
  }
  __syncthreads();
  // inverse DIT, N=2048: stages s=10..0
  for (int s = 10; s >= 0; s--){
    const int h = 2048 >> (s+1);
    for (int bi = t; bi < 1024; bi += 256){
      const int g = bi / h, j = bi - g*h;
      const int i0 = g*2*h + j, i1 = i0 + h;
      float2 p = buf[i0], q = buf[i1];
      float2 w = twid((uint32_t)(j << s), UNIT2K, +1.0f);
      float2 v = cmul(q, w);
      buf[i0] = make_float2(p.x+v.x, p.y+v.y);
      buf[i1] = make_float2(p.x-v.x, p.y-v.y);
    }
    __syncthreads();
  }
  for (int u = t; u < 2048; u += 256){
    int p = f*1024 + u;
    if (p < 32768){
      float hann = 0.5f - 0.5f*cosf(TWOPI_F * (float)u / 2048.0f);
      atomicAdd(&w_res[(size_t)(r*4 + x)*32768 + p],
                buf[u].x * (1.0f/2048.0f) * hann);
    }
  }
}

// ---------------- unit-norm factors over 32768 samples ---------------------
__global__ void k_norm(const float* __restrict__ w_res, float* __restrict__ w_invnorm){
  const int s = blockIdx.x;            // 0..127 = r*4+x
  const float* p = w_res + (size_t)s*32768;
  float acc = 0.0f;
  for (int i = threadIdx.x; i < 32768; i += 256){ float v = p[i]; acc += v*v; }
  __shared__ float red[256];
  red[threadIdx.x] = acc; __syncthreads();
  for (int off = 128; off > 0; off >>= 1){
    if (threadIdx.x < off) red[threadIdx.x] += red[threadIdx.x + off];
    __syncthreads();
  }
  if (threadIdx.x == 0) w_invnorm[s] = 1.0f/(sqrtf(red[0]) + 1e-8f);
}

// --------- forward FFT comb stages (s=0..7), fused input generation --------
// mode 0: res * invnorm (zero-padded) ; mode 1: interp(routed)*noise
__global__ void k_fwdA(const int mode, const float* __restrict__ w_res,
                       const float* __restrict__ w_invnorm,
                       const float* __restrict__ w_routed,
                       float2* __restrict__ spec){
  const int wg = blockIdx.x;
  const int cpair = wg & 127;
  const int sig = wg >> 7;
  const int c0 = cpair*2;
  const int t = threadIdx.x;
  __shared__ float2 buf[2][256];
  const int cc = t & 1;
  const int m0 = t >> 1;
#pragma unroll
  for (int i = 0; i < 2; i++){
    const int m = m0 + i*128;
    const int n = c0 + cc + 256*m;
    float2 val = make_float2(0.0f, 0.0f);
    if (n < 32768){
      if (mode == 0){
        val.x = w_res[(size_t)sig*32768 + n] * w_invnorm[sig];
      } else {
        int lo, hi; float w;
        interp128(n, lo, hi, w);
        const float* rp = w_routed + sig*128;
        float rv = rp[lo]*(1.0f - w) + rp[hi]*w;
        val.x = rv * jax_noise((uint32_t)sig*32768u + (uint32_t)n);
      }
    }
    buf[cc][m] = val;
  }
  __syncthreads();
  const int arr = t & 1;
  const int b = t >> 1;
  for (int s = 0; s < 8; s++){
    const int hl = 128 >> s;                 // local pair distance
    const int g = b / hl, j = b - g*hl;
    const int i0 = g*2*hl + j, i1 = i0 + hl;
    float2 u = buf[arr][i0], v = buf[arr][i1];
    uint32_t e = (((uint32_t)(c0 + arr) + 256u*(uint32_t)j) << s) & 0xFFFFu;
    float2 w = twid(e, UNIT64K, -1.0f);
    buf[arr][i0] = make_float2(u.x+v.x, u.y+v.y);
    float2 d = make_float2(u.x-v.x, u.y-v.y);
    buf[arr][i1] = cmul(d, w);
    __syncthreads();
  }
#pragma unroll
  for (int i = 0; i < 2; i++){
    const int m = m0 + i*128;
    const int n = c0 + cc + 256*m;
    spec[(size_t)sig*65536 + n] = buf[cc][m];
  }
}

// ---------------- forward FFT block stages (s=8..15), in place -------------
__global__ void k_fwdB(float2* __restrict__ spec){
  const int wg = blockIdx.x;
  const int bp = wg & 127;
  const int sig = wg >> 7;
  const int t = threadIdx.x;
  __shared__ float2 buf[512];
  const size_t base = (size_t)sig*65536 + (size_t)bp*512;
  buf[t]       = spec[base + t];
  buf[t + 256] = spec[base + t + 256];
  __syncthreads();
  const int arr = t >> 7, b = t & 127;
  for (int s = 8; s < 16; s++){
    const int hl = 65536 >> (s+1);           // 128..1
    const int g = b / hl, j = b - g*hl;
    const int i0 = arr*256 + g*2*hl + j, i1 = i0 + hl;
    float2 u = buf[i0], v = buf[i1];
    float2 w = twid((uint32_t)(j << s), UNIT64K, -1.0f);
    buf[i0] = make_float2(u.x+v.x, u.y+v.y);
    float2 d = make_float2(u.x-v.x, u.y-v.y);
    buf[i1] = cmul(d, w);
    __syncthreads();
  }
  spec[base + t]       = buf[t];
  spec[base + t + 256] = buf[t + 256];
}

// ------ spectral product + inverse block stages (s=15..8) per combo --------
__global__ void k_prod_invB(const float2* __restrict__ ruspec,
                            const float2* __restrict__ resspec,
                            float2* __restrict__ chunkbuf, const int chunkbase){
  const int wg = blockIdx.x;
  const int bp = wg & 127;
  const int q = wg >> 7;
  const int combo = chunkbase + q;             // ((be*32+r)*4 + x)
  const int x = combo & 3, r = (combo >> 2) & 31, be = combo >> 7;
  const int rus = be*32 + r, ress = r*4 + x;
  const int t = threadIdx.x;
  __shared__ float2 buf[512];
  const size_t ofs = (size_t)bp*512;
#pragma unroll
  for (int i = 0; i < 2; i++){
    const int li = t + i*256;
    float2 a  = ruspec[(size_t)rus*65536 + ofs + li];
    float2 bs = resspec[(size_t)ress*65536 + ofs + li];
    buf[li] = cmul(a, bs);
  }
  __syncthreads();
  const int arr = t >> 7, b = t & 127;
  for (int s = 15; s >= 8; s--){
    const int hl = 65536 >> (s+1);
    const int g = b / hl, j = b - g*hl;
    const int i0 = arr*256 + g*2*hl + j, i1 = i0 + hl;
    float2 p = buf[i0], qv = buf[i1];
    float2 w = twid((uint32_t)(j << s), UNIT64K, +1.0f);
    float2 v = cmul(qv, w);
    buf[i0] = make_float2(p.x+v.x, p.y+v.y);
    buf[i1] = make_float2(p.x-v.x, p.y-v.y);
    __syncthreads();
  }
  chunkbuf[(size_t)q*65536 + ofs + t]       = buf[t];
  chunkbuf[(size_t)q*65536 + ofs + t + 256] = buf[t + 256];
}

// -- inverse comb stages (s=7..0), 4 x-arrays per wg, fused epilogue --------
__global__ void k_invA_w(const float2* __restrict__ chunkbuf, const int chunkbase,
                         const float* __restrict__ w_sm, const float* __restrict__ gains,
                         float* __restrict__ out0){
  const int wg = blockIdx.x;
  const int c = wg & 255;                      // comb id
  const int g = wg >> 8;                       // group within chunk
  const int combo0 = chunkbase + g*4;
  const int be_r = combo0 >> 2;
  const int r = be_r & 31, be = be_r >> 5;
  const int t = threadIdx.x;
  __shared__ float2 buf[4][256];
#pragma unroll
  for (int x = 0; x < 4; x++)
    buf[x][t] = chunkbuf[(size_t)(g*4 + x)*65536 + c + 256*t];
  __syncthreads();
  for (int s = 7; s >= 0; s--){
    const int hl = 128 >> s;                   // local distance 1..128
    for (int task = t; task < 512; task += 256){
      const int arr = task >> 7, b = task & 127;
      const int g2 = b / hl, j = b - g2*hl;
      const int i0 = g2*2*hl + j, i1 = i0 + hl;
      float2 p = buf[arr][i0], q = buf[arr][i1];
      uint32_t e = (((uint32_t)(c + 256*j)) << s) & 0xFFFFu;
      float2 w = twid(e, UNIT64K, +1.0f);
      float2 v = cmul(q, w);
      buf[arr][i0] = make_float2(p.x+v.x, p.y+v.y);
      buf[arr][i1] = make_float2(p.x-v.x, p.y-v.y);
    }
    __syncthreads();
  }
  if (t < 128){
    const int tt = c + 256*t;                  // < 32768
    int lo, hi; float w;
    interp128(tt, lo, hi, w);
    float val = 0.0f;
#pragma unroll
    for (int x = 0; x < 4; x++){
      const float* smp = w_sm + (be*4 + x)*128;
      float dw = smp[lo]*(1.0f - w) + smp[hi]*w;
      val += dw * buf[x][t].x;
    }
    val *= (1.0f/65536.0f);                    // inverse FFT scale
    float gv = fabsf(gains[r]);
    atomicAdd(&out0[(size_t)be*32768 + tt], tanhf(val*gv));
  }
}

extern "C" void kernel_launch(void* const* d_in, const int* in_sizes, int n_in,
                              void* d_out, int out_size, void* d_ws, size_t ws_size,
                              hipStream_t stream){
  const float* ctrl   = (const float*)d_in[0];
  const float* defm   = (const float*)d_in[1];
  const float* router = (const float*)d_in[2];
  const float* amp    = (const float*)d_in[3];
  const float* phase  = (const float*)d_in[4];
  const float* decay  = (const float*)d_in[5];
  const float* gains  = (const float*)d_in[6];
  float* out = (float*)d_out;
  float* ws  = (float*)d_ws;

  // ws layout (float offsets)
  float*  w_res     = ws;                         // 128*32768
  float*  w_routed  = ws + 4194304;               // 32768
  float*  w_sm      = ws + 4227072;               // 4096
  float*  w_invnorm = ws + 4231168;               // 128
  float2* w_ruspec  = (float2*)(ws + 4231296);    // 256*65536 c
  float2* w_resspec = (float2*)(ws + 37785728);   // 128*65536 c
  float2* w_chunk   = (float2*)(ws + 54562944);   // CHUNK*65536 c
  const size_t base_f = 54562944;

  int CHUNK = 0;
  for (int cgo = 256; cgo >= 4; cgo >>= 1){
    size_t need = (base_f + (size_t)cgo*131072) * sizeof(float);
    if (need <= ws_size){ CHUNK = cgo; break; }
  }

  hipMemsetAsync(d_out, 0, 262144*sizeof(float), stream);  // summed (atomicAdd)
  k_routed<<<132, 256, 0, stream>>>(ctrl, defm, router, w_routed, w_sm, out + 262144);
  if (CHUNK == 0) return;  // diagnostic: out1 ok, out0 stays 0 => ws too small

  hipMemsetAsync(w_res, 0, 4194304*sizeof(float), stream);
  k_frames<<<4096, 256, 0, stream>>>(amp, phase, decay, w_res);
  k_norm<<<128, 256, 0, stream>>>(w_res, w_invnorm);
  k_fwdA<<<128*128, 256, 0, stream>>>(0, w_res, w_invnorm, w_routed, w_resspec);
  k_fwdB<<<128*128, 256, 0, stream>>>(w_resspec);
  k_fwdA<<<256*128, 256, 0, stream>>>(1, w_res, w_invnorm, w_routed, w_ruspec);
  k_fwdB<<<256*128, 256, 0, stream>>>(w_ruspec);
  for (int cb = 0; cb < 1024; cb += CHUNK){
    k_prod_invB<<<CHUNK*128, 256, 0, stream>>>(w_ruspec, w_resspec, w_chunk, cb);
    k_invA_w<<<(CHUNK/4)*256, 256, 0, stream>>>(w_chunk, cb, w_sm, gains, out);
  }
}

// Round 2
// 1032.119 us; speedup vs baseline: 1.4520x; 1.4520x over previous
//
#include <hip/hip_runtime.h>
#include <stdint.h>

// ResonanceLayer: routed einsum -> resonance irfft/OLA (x-pair packed) ->
// unit-norm -> upsample*threefry-noise -> 65536-pt FFT convolution with
// complex-packed res spectra (512 inverse FFTs) -> softmax-deformation mix ->
// tanh(gain*x) summed over resonators.
//
// FFT: radix-2 DIF forward (natural->bitrev), DIT inverse (bitrev->natural);
// spectra stay in bitrev order (products are order-consistent).
// 65536 = comb stages (pairs in m, per comb c; n = c + 256*m) + block stages
// (pairs in c, per m). Spectra stored c-major [c*256+m] so comb kernels write
// contiguous rows; block kernel works in place on 8-m slabs (64B-granular).
// Chunk intermediates stored n-major [m*256+c] (prod writes rows, invA reads
// 64B clusters via 8-comb blocks).

#define PI_F     3.14159265358979323846f
#define TWOPI_F  6.28318530717958647692f
#define UNIT64K  (TWOPI_F/65536.0f)
#define UNIT2K   (TWOPI_F/2048.0f)
#define SK(i)    ((i) + ((i) >> 5))      // LDS skew: kills 4-way bank conflicts

__device__ __forceinline__ float2 cmul(float2 a, float2 b){
  return make_float2(a.x*b.x - a.y*b.y, a.x*b.y + a.y*b.x);
}

__device__ __forceinline__ float2 twid(uint32_t e, float unit, float sign){
  float ang = (float)e * unit;
  float sn, cn;
  __sincosf(ang, &sn, &cn);
  return make_float2(cn, sign*sn);
}

__device__ __forceinline__ uint32_t rotl32(uint32_t v, int r){
  return (v << r) | (v >> (32 - r));
}

// Threefry-2x32, key = (0, 123)
__device__ __forceinline__ void threefry2x32(uint32_t c0, uint32_t c1,
                                             uint32_t& o0, uint32_t& o1){
  const uint32_t k0 = 0u, k1 = 123u;
  const uint32_t k2 = 0x1BD11BDAu ^ k0 ^ k1;
  const uint32_t ks[3] = {k0, k1, k2};
  uint32_t x0 = c0 + k0, x1 = c1 + k1;
#pragma unroll
  for (int i = 0; i < 5; i++){
    if ((i & 1) == 0){
      x0 += x1; x1 = rotl32(x1,13); x1 ^= x0;
      x0 += x1; x1 = rotl32(x1,15); x1 ^= x0;
      x0 += x1; x1 = rotl32(x1,26); x1 ^= x0;
      x0 += x1; x1 = rotl32(x1, 6); x1 ^= x0;
    } else {
      x0 += x1; x1 = rotl32(x1,17); x1 ^= x0;
      x0 += x1; x1 = rotl32(x1,29); x1 ^= x0;
      x0 += x1; x1 = rotl32(x1,16); x1 ^= x0;
      x0 += x1; x1 = rotl32(x1,24); x1 ^= x0;
    }
    x0 += ks[(i+1)%3];
    x1 += ks[(i+2)%3] + (uint32_t)(i+1);
  }
  o0 = x0; o1 = x1;
}

__device__ __forceinline__ float jax_noise(uint32_t p){
  uint32_t b0, b1;
  threefry2x32(0u, p, b0, b1);
  uint32_t bits = b0 ^ b1;
  float u = __uint_as_float((bits >> 9) | 0x3f800000u) - 1.0f;
  return fmaxf(-1.0f, u*2.0f - 1.0f);
}

__device__ __forceinline__ void interp128(int t, int& lo, int& hi, float& w){
  float posf = ((float)t + 0.5f) * (1.0f/256.0f) - 0.5f;
  posf = fminf(fmaxf(posf, 0.0f), 127.0f);
  lo = (int)posf;
  hi = lo + 1; if (hi > 127) hi = 127;
  w = posf - (float)lo;
}

// ---------------- routed einsum + output1 + softmax(deformations) ----------
__global__ void k_routed(const float* __restrict__ ctrl, const float* __restrict__ defm,
                         const float* __restrict__ router,
                         float* __restrict__ w_routed, float* __restrict__ w_sm,
                         float* __restrict__ out1){
  int idx = blockIdx.x*blockDim.x + threadIdx.x;
  if (idx < 32768){
    int f = idx & 127, r = (idx >> 7) & 31, be = idx >> 12;
    float acc = 0.0f;
#pragma unroll
    for (int c = 0; c < 16; c++)
      acc += ctrl[(be*16 + c)*128 + f] * router[c*32 + r];
    w_routed[idx] = acc;
    out1[idx] = acc;
  } else if (idx < 32768 + 1024){
    int j = idx - 32768;
    int f = j & 127, be = j >> 7;
    float v[4];
#pragma unroll
    for (int x = 0; x < 4; x++)
      v[x] = defm[(be*4 + x)*128 + f] + (x == 0 ? 1.0f : 0.0f);
    float mx = fmaxf(fmaxf(v[0], v[1]), fmaxf(v[2], v[3]));
    float s = 0.0f;
#pragma unroll
    for (int x = 0; x < 4; x++){ v[x] = expf(v[x] - mx); s += v[x]; }
#pragma unroll
    for (int x = 0; x < 4; x++) w_sm[(be*4 + x)*128 + f] = v[x]/s;
  }
}

// ---- resonance frames: packed complex irfft(2048) of x-pairs + hann + OLA --
// w_resT layout: [channel s=r*4+x][c*128 + m], time n = c + 256*m
__global__ void k_frames(const float* __restrict__ amp, const float* __restrict__ phase,
                         const float* __restrict__ decay, float* __restrict__ w_resT){
  const int wg = blockIdx.x;          // (r,p,f)
  const int f = wg & 31;
  const int p = (wg >> 5) & 1;
  const int r = wg >> 6;
  const int t = threadIdx.x;
  __shared__ float2 buf[2048];

  for (int k = t; k <= 1024; k += 256){
    float2 S[2];
#pragma unroll
    for (int d = 0; d < 2; d++){
      const int x = 2*p + d;
      const int base = (r*1025 + k)*4 + x;
      float a  = fabsf(amp[base]);
      float ph = tanhf(phase[base]) * PI_F;
      float sg = 1.0f / (1.0f + expf(-decay[base]));
      float dc = 0.5f + 0.45f * sg;
      float mag = expf(logf(dc + 1e-12f) * (float)(f+1)) * a;
      float snv, csv;
      sincosf(ph, &snv, &csv);
      float re = mag * csv, im = mag * snv;
      if (k == 0 || k == 1024) im = 0.0f;
      S[d] = make_float2(re, im);
    }
    // z = S0 + i*S1 at k;  conj(S0) + i*conj(S1) at 2048-k
    buf[__brev((uint32_t)k) >> 21] =
        make_float2(S[0].x - S[1].y, S[0].y + S[1].x);
    if (k >= 1 && k <= 1023)
      buf[__brev((uint32_t)(2048 - k)) >> 21] =
          make_float2(S[0].x + S[1].y, -S[0].y + S[1].x);
  }
  __syncthreads();
  for (int s = 10; s >= 0; s--){
    const int ls = 10 - s;
    const int hl = 1 << ls;
    for (int bi = t; bi < 1024; bi += 256){
      const int g = bi >> ls, j = bi & (hl - 1);
      const int i0 = g*2*hl + j, i1 = i0 + hl;
      float2 pp = buf[i0], qq = buf[i1];
      float2 w = twid((uint32_t)(j << s), UNIT2K, +1.0f);
      float2 v = cmul(qq, w);
      buf[i0] = make_float2(pp.x+v.x, pp.y+v.y);
      buf[i1] = make_float2(pp.x-v.x, pp.y-v.y);
    }
    __syncthreads();
  }
  for (int u = t; u < 2048; u += 256){
    int pt = f*1024 + u;
    if (pt < 32768){
      float hann = 0.5f - 0.5f*cosf(TWOPI_F * (float)u / 2048.0f);
      float sc = (1.0f/2048.0f) * hann;
      const int c = pt & 255, m = pt >> 8;
      atomicAdd(&w_resT[(size_t)(r*4 + 2*p    )*32768 + c*128 + m], buf[u].x*sc);
      atomicAdd(&w_resT[(size_t)(r*4 + 2*p + 1)*32768 + c*128 + m], buf[u].y*sc);
    }
  }
}

// ---------------- unit-norm factors over 32768 samples ---------------------
__global__ void k_norm(const float* __restrict__ w_resT, float* __restrict__ w_invnorm){
  const int s = blockIdx.x;            // 0..127 = r*4+x
  const float* p = w_resT + (size_t)s*32768;
  float acc = 0.0f;
  for (int i = threadIdx.x; i < 32768; i += 256){ float v = p[i]; acc += v*v; }
  __shared__ float red[256];
  red[threadIdx.x] = acc; __syncthreads();
  for (int off = 128; off > 0; off >>= 1){
    if (threadIdx.x < off) red[threadIdx.x] += red[threadIdx.x + off];
    __syncthreads();
  }
  if (threadIdx.x == 0) w_invnorm[s] = 1.0f/(sqrtf(red[0]) + 1e-8f);
}

// --------- forward comb stages (s=0..7): 256-pt DIF over m per comb --------
// mode 0 (sig=r*2+p <64): packed res pair -> RESP;  mode 1 (sig<256): ru real
// output c-major: spec[sig][c*256 + m]  (contiguous 2KB rows per comb)
__global__ void k_fwdA(const int mode, const float* __restrict__ w_resT,
                       const float* __restrict__ w_invnorm,
                       const float* __restrict__ w_routed,
                       float2* __restrict__ spec){
  const int wg = blockIdx.x;
  const int cpair = wg & 127;
  const int sig = wg >> 7;
  const int c0 = cpair*2;
  const int t = threadIdx.x;
  __shared__ float re[2][264], im[2][264];
#pragma unroll
  for (int i = 0; i < 2; i++){
    const int li = t + i*256;
    const int cc = li >> 8, m = li & 255;
    const int c = c0 + cc;
    float vx = 0.0f, vy = 0.0f;
    if (m < 128){                       // n = c + 256*m < 32768
      if (mode == 0){
        const int rr = sig >> 1, pq = sig & 1;
        const int ch0 = rr*4 + pq*2;
        vx = w_resT[(size_t)ch0*32768 + c*128 + m] * w_invnorm[ch0];
        vy = w_resT[(size_t)(ch0+1)*32768 + c*128 + m] * w_invnorm[ch0+1];
      } else {
        const int n = c + 256*m;
        int lo, hi; float w;
        interp128(n, lo, hi, w);
        const float* rp = w_routed + sig*128;
        float rv = rp[lo]*(1.0f - w) + rp[hi]*w;
        vx = rv * jax_noise((uint32_t)sig*32768u + (uint32_t)n);
      }
    }
    re[cc][SK(m)] = vx; im[cc][SK(m)] = vy;
  }
  __syncthreads();
  const int arr = t >> 7, b = t & 127;
  for (int s = 0; s < 8; s++){
    const int ls = 7 - s;
    const int hl = 1 << ls;
    const int g = b >> ls, j = b & (hl - 1);
    const int i0 = g*2*hl + j, i1 = i0 + hl;
    float2 u = make_float2(re[arr][SK(i0)], im[arr][SK(i0)]);
    float2 v = make_float2(re[arr][SK(i1)], im[arr][SK(i1)]);
    uint32_t e = (((uint32_t)(c0 + arr) + 256u*(uint32_t)j) << s) & 0xFFFFu;
    float2 w = twid(e, UNIT64K, -1.0f);
    re[arr][SK(i0)] = u.x + v.x; im[arr][SK(i0)] = u.y + v.y;
    float2 d = make_float2(u.x - v.x, u.y - v.y);
    float2 dv = cmul(d, w);
    re[arr][SK(i1)] = dv.x; im[arr][SK(i1)] = dv.y;
    __syncthreads();
  }
#pragma unroll
  for (int i = 0; i < 2; i++){
    const int li = t + i*256;
    const int cc = li >> 8, m = li & 255;
    spec[(size_t)sig*65536 + (size_t)(c0+cc)*256 + m] =
        make_float2(re[cc][SK(m)], im[cc][SK(m)]);
  }
}

// ------- forward block stages (s=8..15): 256-pt DIF over c per m, in place --
// block = (sig, mq): 8 m-slabs; reads/writes 64B runs, element set private
__global__ void k_fwdB(float2* __restrict__ spec){
  const int wg = blockIdx.x;
  const int mq = wg & 31;
  const int sig = wg >> 5;
  const int m8 = mq*8;
  const int t = threadIdx.x;
  __shared__ float re[8][264], im[8][264];
  float2* base = spec + (size_t)sig*65536;
#pragma unroll
  for (int i = 0; i < 8; i++){
    const int li = t + i*256;          // li = c*8 + mm
    const int mm = li & 7, c = li >> 3;
    float2 v = base[(size_t)c*256 + m8 + mm];
    re[mm][SK(c)] = v.x; im[mm][SK(c)] = v.y;
  }
  __syncthreads();
  for (int s = 8; s < 16; s++){
    const int ls = 15 - s;
    const int hl = 1 << ls;            // 128..1
#pragma unroll
    for (int it = 0; it < 4; it++){
      const int task = t + it*256;
      const int arr = task >> 7, b = task & 127;
      const int g = b >> ls, j = b & (hl - 1);
      const int i0 = g*2*hl + j, i1 = i0 + hl;
      float2 u = make_float2(re[arr][SK(i0)], im[arr][SK(i0)]);
      float2 v = make_float2(re[arr][SK(i1)], im[arr][SK(i1)]);
      float2 w = twid((uint32_t)(j << s), UNIT64K, -1.0f);
      re[arr][SK(i0)] = u.x + v.x; im[arr][SK(i0)] = u.y + v.y;
      float2 d = make_float2(u.x - v.x, u.y - v.y);
      float2 dv = cmul(d, w);
      re[arr][SK(i1)] = dv.x; im[arr][SK(i1)] = dv.y;
    }
    __syncthreads();
  }
#pragma unroll
  for (int i = 0; i < 8; i++){
    const int li = t + i*256;
    const int mm = li & 7, c = li >> 3;
    base[(size_t)c*256 + m8 + mm] = make_float2(re[mm][SK(c)], im[mm][SK(c)]);
  }
}

// -- product + inverse block stages (s=15..8): per packed combo q, 8-m slab --
// chunk n-major: CH[q][m*256 + c]  (contiguous rows per m)
__global__ void k_prod_invB(const float2* __restrict__ ruspec,
                            const float2* __restrict__ respspec,
                            float2* __restrict__ chunkbuf, const int gbase){
  const int wg = blockIdx.x;
  const int mq = wg & 31;
  const int q = wg >> 5;               // local packed combo: (gl, p)
  const int g = gbase + (q >> 1), p = q & 1;
  const int r = g & 31;
  const int rp = r*2 + p;
  const int m8 = mq*8;
  const int t = threadIdx.x;
  __shared__ float re[8][264], im[8][264];
  const float2* A = ruspec + (size_t)g*65536;
  const float2* B = respspec + (size_t)rp*65536;
#pragma unroll
  for (int i = 0; i < 8; i++){
    const int li = t + i*256;          // li = c*8 + mm
    const int mm = li & 7, c = li >> 3;
    const size_t a = (size_t)c*256 + m8 + mm;
    float2 v = cmul(A[a], B[a]);
    re[mm][SK(c)] = v.x; im[mm][SK(c)] = v.y;
  }
  __syncthreads();
  for (int s = 15; s >= 8; s--){
    const int ls = 15 - s;
    const int hl = 1 << ls;            // 1..128
#pragma unroll
    for (int it = 0; it < 4; it++){
      const int task = t + it*256;
      const int arr = task >> 7, b = task & 127;
      const int g2 = b >> ls, j = b & (hl - 1);
      const int i0 = g2*2*hl + j, i1 = i0 + hl;
      float2 pp = make_float2(re[arr][SK(i0)], im[arr][SK(i0)]);
      float2 qq = make_float2(re[arr][SK(i1)], im[arr][SK(i1)]);
      float2 w = twid((uint32_t)(j << s), UNIT64K, +1.0f);
      float2 v = cmul(qq, w);
      re[arr][SK(i0)] = pp.x + v.x; im[arr][SK(i0)] = pp.y + v.y;
      re[arr][SK(i1)] = pp.x - v.x; im[arr][SK(i1)] = pp.y - v.y;
    }
    __syncthreads();
  }
  float2* O = chunkbuf + (size_t)q*65536;
#pragma unroll
  for (int i = 0; i < 8; i++){
    const int li = t + i*256;          // li = mm*256 + c -> contiguous rows
    const int mm = li >> 8, c = li & 255;
    O[(size_t)(m8+mm)*256 + c] = make_float2(re[mm][SK(c)], im[mm][SK(c)]);
  }
}

// -- inverse comb stages (s=7..0): 8 combs x 2 p per block, fused epilogue --
__global__ void k_invA_w(const float2* __restrict__ chunkbuf, const int gbase,
                         const float* __restrict__ w_sm, const float* __restrict__ gains,
                         float* __restrict__ out0){
  const int wg = blockIdx.x;
  const int c8 = wg & 31;
  const int gl = wg >> 5;
  const int g = gbase + gl;
  const int r = g & 31, be = g >> 5;
  const int c0 = c8*8;
  const int t = threadIdx.x;
  __shared__ float re[2][8][264], im[2][8][264];
#pragma unroll
  for (int p = 0; p < 2; p++){
    const float2* C = chunkbuf + (size_t)(gl*2 + p)*65536;
#pragma unroll
    for (int i = 0; i < 8; i++){
      const int li = t + i*256;        // li = m*8 + cc -> 64B clusters
      const int cc = li & 7, m = li >> 3;
      float2 v = C[(size_t)m*256 + c0 + cc];
      re[p][cc][SK(m)] = v.x; im[p][cc][SK(m)] = v.y;
    }
  }
  __syncthreads();
  for (int s = 7; s >= 0; s--){
    const int ls = 7 - s;
    const int hl = 1 << ls;            // 1..128
#pragma unroll
    for (int it = 0; it < 8; it++){
      const int task = t + it*256;     // p(1) cc(3) b(7)
      const int b = task & 127;
      const int cc = (task >> 7) & 7;
      const int p = task >> 10;
      const int g2 = b >> ls, j = b & (hl - 1);
      const int i0 = g2*2*hl + j, i1 = i0 + hl;
      float2 pp = make_float2(re[p][cc][SK(i0)], im[p][cc][SK(i0)]);
      float2 qq = make_float2(re[p][cc][SK(i1)], im[p][cc][SK(i1)]);
      uint32_t e = (((uint32_t)(c0 + cc) + 256u*(uint32_t)j) << s) & 0xFFFFu;
      float2 w = twid(e, UNIT64K, +1.0f);
      float2 v = cmul(qq, w);
      re[p][cc][SK(i0)] = pp.x + v.x; im[p][cc][SK(i0)] = pp.y + v.y;
      re[p][cc][SK(i1)] = pp.x - v.x; im[p][cc][SK(i1)] = pp.y - v.y;
    }
    __syncthreads();
  }
  const float gv = fabsf(gains[r]);
  const float* smb = w_sm + be*512;
#pragma unroll
  for (int it = 0; it < 4; it++){
    const int li = t + it*256;         // li = m*8 + cc, m < 128
    const int cc = li & 7, m = li >> 3;
    const int tt = c0 + cc + 256*m;
    int lo, hi; float w;
    interp128(tt, lo, hi, w);
    float val = 0.0f;
#pragma unroll
    for (int p = 0; p < 2; p++){
      float z_re = re[p][cc][SK(m)], z_im = im[p][cc][SK(m)];
      float dw0 = smb[(2*p  )*128 + lo]*(1.0f - w) + smb[(2*p  )*128 + hi]*w;
      float dw1 = smb[(2*p+1)*128 + lo]*(1.0f - w) + smb[(2*p+1)*128 + hi]*w;
      val += dw0*z_re + dw1*z_im;
    }
    val *= (1.0f/65536.0f);
    atomicAdd(&out0[(size_t)be*32768 + tt], tanhf(val*gv));
  }
}

extern "C" void kernel_launch(void* const* d_in, const int* in_sizes, int n_in,
                              void* d_out, int out_size, void* d_ws, size_t ws_size,
                              hipStream_t stream){
  const float* ctrl   = (const float*)d_in[0];
  const float* defm   = (const float*)d_in[1];
  const float* router = (const float*)d_in[2];
  const float* amp    = (const float*)d_in[3];
  const float* phase  = (const float*)d_in[4];
  const float* decay  = (const float*)d_in[5];
  const float* gains  = (const float*)d_in[6];
  float* out = (float*)d_out;
  float* ws  = (float*)d_ws;

  // ws layout (float offsets)
  float*  w_resT    = ws;                         // 128*32768      = 4,194,304
  float*  w_routed  = ws + 4194304;               // 32768
  float*  w_sm      = ws + 4227072;               // 4096
  float*  w_invnorm = ws + 4231168;               // 128
  float2* w_ruspec  = (float2*)(ws + 4231296);    // 256*65536 c    = 33,554,432 f
  float2* w_resp    = (float2*)(ws + 37785728);   // 64*65536 c     = 8,388,608 f
  float2* w_chunk   = (float2*)(ws + 46174336);   // 2G*65536 c
  const size_t base_f = 46174336;

  int G = 0;
  for (int gg = 64; gg >= 1; gg >>= 1){
    size_t need = (base_f + (size_t)gg*262144) * sizeof(float);
    if (need <= ws_size){ G = gg; break; }
  }

  hipMemsetAsync(d_out, 0, 262144*sizeof(float), stream);  // out0 (atomicAdd)
  k_routed<<<132, 256, 0, stream>>>(ctrl, defm, router, w_routed, w_sm, out + 262144);
  if (G == 0) return;  // diagnostic: out1 ok, out0 stays 0 => ws too small

  hipMemsetAsync(w_resT, 0, 4194304*sizeof(float), stream);
  k_frames<<<2048, 256, 0, stream>>>(amp, phase, decay, w_resT);
  k_norm<<<128, 256, 0, stream>>>(w_resT, w_invnorm);
  k_fwdA<<<64*128, 256, 0, stream>>>(0, w_resT, w_invnorm, w_routed, w_resp);
  k_fwdB<<<64*32, 256, 0, stream>>>(w_resp);
  k_fwdA<<<256*128, 256, 0, stream>>>(1, w_resT, w_invnorm, w_routed, w_ruspec);
  k_fwdB<<<256*32, 256, 0, stream>>>(w_ruspec);
  for (int gb = 0; gb < 256; gb += G){
    k_prod_invB<<<G*2*32, 256, 0, stream>>>(w_ruspec, w_resp, w_chunk, gb);
    k_invA_w<<<G*32, 256, 0, stream>>>(w_chunk, gb, w_sm, gains, out);
  }
}

// Round 3
// 626.805 us; speedup vs baseline: 2.3909x; 1.6466x over previous
//
#include <hip/hip_runtime.h>
#include <stdint.h>

// ResonanceLayer: routed einsum -> resonance irfft (x-pair packed, frames to
// scratch) -> OLA+transpose+norm -> upsample*threefry-noise -> 65536-pt FFT
// convolution with complex-packed res spectra -> softmax-deformation mix ->
// tanh(gain*x) summed over resonators.
//
// FFT: radix-2 DIF forward (natural->bitrev), DIT inverse (bitrev->natural);
// spectra stay in bitrev order (products are order-consistent).
// Spectra stored c-major [c*256+m] (comb kernels write contiguous rows);
// block kernel works in place on 8-m slabs. Chunk intermediates n-major.
// k_frames writes frames contiguously (NO transposed atomics -- that was the
// round-2 bottleneck: 512B-strided atomicAdd = 258MB RMW @ 0.65 TB/s);
// k_ola does overlap-add + transpose via LDS tile with coalesced IO.

#define PI_F     3.14159265358979323846f
#define TWOPI_F  6.28318530717958647692f
#define UNIT64K  (TWOPI_F/65536.0f)
#define UNIT2K   (TWOPI_F/2048.0f)
#define SK(i)    ((i) + ((i) >> 5))      // LDS skew: kills 4-way bank conflicts

__device__ __forceinline__ float2 cmul(float2 a, float2 b){
  return make_float2(a.x*b.x - a.y*b.y, a.x*b.y + a.y*b.x);
}

__device__ __forceinline__ float2 twid(uint32_t e, float unit, float sign){
  float ang = (float)e * unit;
  float sn, cn;
  __sincosf(ang, &sn, &cn);
  return make_float2(cn, sign*sn);
}

__device__ __forceinline__ uint32_t rotl32(uint32_t v, int r){
  return (v << r) | (v >> (32 - r));
}

// Threefry-2x32, key = (0, 123)
__device__ __forceinline__ void threefry2x32(uint32_t c0, uint32_t c1,
                                             uint32_t& o0, uint32_t& o1){
  const uint32_t k0 = 0u, k1 = 123u;
  const uint32_t k2 = 0x1BD11BDAu ^ k0 ^ k1;
  const uint32_t ks[3] = {k0, k1, k2};
  uint32_t x0 = c0 + k0, x1 = c1 + k1;
#pragma unroll
  for (int i = 0; i < 5; i++){
    if ((i & 1) == 0){
      x0 += x1; x1 = rotl32(x1,13); x1 ^= x0;
      x0 += x1; x1 = rotl32(x1,15); x1 ^= x0;
      x0 += x1; x1 = rotl32(x1,26); x1 ^= x0;
      x0 += x1; x1 = rotl32(x1, 6); x1 ^= x0;
    } else {
      x0 += x1; x1 = rotl32(x1,17); x1 ^= x0;
      x0 += x1; x1 = rotl32(x1,29); x1 ^= x0;
      x0 += x1; x1 = rotl32(x1,16); x1 ^= x0;
      x0 += x1; x1 = rotl32(x1,24); x1 ^= x0;
    }
    x0 += ks[(i+1)%3];
    x1 += ks[(i+2)%3] + (uint32_t)(i+1);
  }
  o0 = x0; o1 = x1;
}

__device__ __forceinline__ float jax_noise(uint32_t p){
  uint32_t b0, b1;
  threefry2x32(0u, p, b0, b1);
  uint32_t bits = b0 ^ b1;
  float u = __uint_as_float((bits >> 9) | 0x3f800000u) - 1.0f;
  return fmaxf(-1.0f, u*2.0f - 1.0f);
}

__device__ __forceinline__ void interp128(int t, int& lo, int& hi, float& w){
  float posf = ((float)t + 0.5f) * (1.0f/256.0f) - 0.5f;
  posf = fminf(fmaxf(posf, 0.0f), 127.0f);
  lo = (int)posf;
  hi = lo + 1; if (hi > 127) hi = 127;
  w = posf - (float)lo;
}

// ---------------- routed einsum + output1 + softmax(deformations) ----------
__global__ void k_routed(const float* __restrict__ ctrl, const float* __restrict__ defm,
                         const float* __restrict__ router,
                         float* __restrict__ w_routed, float* __restrict__ w_sm,
                         float* __restrict__ out1){
  int idx = blockIdx.x*blockDim.x + threadIdx.x;
  if (idx < 32768){
    int f = idx & 127, r = (idx >> 7) & 31, be = idx >> 12;
    float acc = 0.0f;
#pragma unroll
    for (int c = 0; c < 16; c++)
      acc += ctrl[(be*16 + c)*128 + f] * router[c*32 + r];
    w_routed[idx] = acc;
    out1[idx] = acc;
  } else if (idx < 32768 + 1024){
    int j = idx - 32768;
    int f = j & 127, be = j >> 7;
    float v[4];
#pragma unroll
    for (int x = 0; x < 4; x++)
      v[x] = defm[(be*4 + x)*128 + f] + (x == 0 ? 1.0f : 0.0f);
    float mx = fmaxf(fmaxf(v[0], v[1]), fmaxf(v[2], v[3]));
    float s = 0.0f;
#pragma unroll
    for (int x = 0; x < 4; x++){ v[x] = expf(v[x] - mx); s += v[x]; }
#pragma unroll
    for (int x = 0; x < 4; x++) w_sm[(be*4 + x)*128 + f] = v[x]/s;
  }
}

// ---- resonance frames: packed complex irfft(2048) of x-pairs + hann -------
// output: w_fr[(rp*32+f)*2048 + u]  (contiguous float2 per frame, no atomics)
__global__ void k_frames(const float* __restrict__ amp, const float* __restrict__ phase,
                         const float* __restrict__ decay, float2* __restrict__ w_fr){
  const int wg = blockIdx.x;          // (r,p,f)
  const int f = wg & 31;
  const int rp = wg >> 5;             // r*2 + p
  const int p = rp & 1;
  const int r = rp >> 1;
  const int t = threadIdx.x;
  __shared__ float2 buf[2048];

  for (int k = t; k <= 1024; k += 256){
    float2 S[2];
#pragma unroll
    for (int d = 0; d < 2; d++){
      const int x = 2*p + d;
      const int base = (r*1025 + k)*4 + x;
      float a  = fabsf(amp[base]);
      float ph = tanhf(phase[base]) * PI_F;
      float sg = 1.0f / (1.0f + expf(-decay[base]));
      float dc = 0.5f + 0.45f * sg;
      float mag = expf(logf(dc + 1e-12f) * (float)(f+1)) * a;
      float snv, csv;
      sincosf(ph, &snv, &csv);
      float re = mag * csv, im = mag * snv;
      if (k == 0 || k == 1024) im = 0.0f;
      S[d] = make_float2(re, im);
    }
    // z = S0 + i*S1 at k;  conj(S0) + i*conj(S1) at 2048-k
    buf[__brev((uint32_t)k) >> 21] =
        make_float2(S[0].x - S[1].y, S[0].y + S[1].x);
    if (k >= 1 && k <= 1023)
      buf[__brev((uint32_t)(2048 - k)) >> 21] =
          make_float2(S[0].x + S[1].y, -S[0].y + S[1].x);
  }
  __syncthreads();
  for (int s = 10; s >= 0; s--){
    const int ls = 10 - s;
    const int hl = 1 << ls;
    for (int bi = t; bi < 1024; bi += 256){
      const int g = bi >> ls, j = bi & (hl - 1);
      const int i0 = g*2*hl + j, i1 = i0 + hl;
      float2 pp = buf[i0], qq = buf[i1];
      float2 w = twid((uint32_t)(j << s), UNIT2K, +1.0f);
      float2 v = cmul(qq, w);
      buf[i0] = make_float2(pp.x+v.x, pp.y+v.y);
      buf[i1] = make_float2(pp.x-v.x, pp.y-v.y);
    }
    __syncthreads();
  }
  float2* O = w_fr + (size_t)wg*2048;
  for (int u = t; u < 2048; u += 256){
    float hann = 0.5f - 0.5f*cosf(TWOPI_F * (float)u / 2048.0f);
    float sc = (1.0f/2048.0f) * hann;
    O[u] = make_float2(buf[u].x*sc, buf[u].y*sc);
  }
}

// ---- OLA + transpose + sum-of-squares ------------------------------------
// in:  w_fr[(rp*32+f)*2048 + u]  out: w_resT[ch][c*128+m], n = c + 256*m
__global__ void k_ola(const float2* __restrict__ w_fr, float* __restrict__ w_resT,
                      float* __restrict__ w_sumsq){
  const int wg = blockIdx.x;           // rp*8 + cq
  const int cq = wg & 7;
  const int rp = wg >> 3;
  const int c0 = cq*32;
  const int r = rp >> 1, p = rp & 1;
  const int ch0 = r*4 + p*2;
  const int t = threadIdx.x;
  __shared__ float tx[32][129], ty[32][129];
  __shared__ float red[2][256];
  const float2* F = w_fr + (size_t)rp*32*2048;
  float acc0 = 0.0f, acc1 = 0.0f;
#pragma unroll
  for (int it = 0; it < 16; it++){
    const int idx = it*256 + t;        // m*32 + c'  (time-ordered reads)
    const int cp = idx & 31, m = idx >> 5;
    const int n = c0 + cp + 256*m;
    const int f = n >> 10, u = n & 1023;
    float2 a = F[(size_t)f*2048 + u];
    float vx = a.x, vy = a.y;
    if (f > 0){
      float2 b = F[(size_t)(f-1)*2048 + u + 1024];
      vx += b.x; vy += b.y;
    }
    tx[cp][m] = vx; ty[cp][m] = vy;
    acc0 += vx*vx; acc1 += vy*vy;
  }
  red[0][t] = acc0; red[1][t] = acc1;
  __syncthreads();
#pragma unroll
  for (int it = 0; it < 16; it++){
    const int idx = it*256 + t;        // c'*128 + m  (contiguous writes)
    const int m = idx & 127, cp = idx >> 7;
    w_resT[(size_t)ch0*32768 + (size_t)(c0+cp)*128 + m]     = tx[cp][m];
    w_resT[(size_t)(ch0+1)*32768 + (size_t)(c0+cp)*128 + m] = ty[cp][m];
  }
  for (int off = 128; off > 0; off >>= 1){
    __syncthreads();
    if (t < off){ red[0][t] += red[0][t+off]; red[1][t] += red[1][t+off]; }
  }
  if (t == 0){
    atomicAdd(&w_sumsq[ch0],     red[0][0]);
    atomicAdd(&w_sumsq[ch0 + 1], red[1][0]);
  }
}

// ---------------- invnorm from sumsq (1 tiny block) ------------------------
__global__ void k_norm(const float* __restrict__ w_sumsq, float* __restrict__ w_invnorm){
  const int s = threadIdx.x;
  if (s < 128) w_invnorm[s] = 1.0f/(sqrtf(w_sumsq[s]) + 1e-8f);
}

// --------- forward comb stages (s=0..7): 256-pt DIF over m per comb --------
// mode 0 (sig=r*2+p <64): packed res pair -> RESP;  mode 1 (sig<256): ru real
// output c-major: spec[sig][c*256 + m]  (contiguous 2KB rows per comb)
__global__ void k_fwdA(const int mode, const float* __restrict__ w_resT,
                       const float* __restrict__ w_invnorm,
                       const float* __restrict__ w_routed,
                       float2* __restrict__ spec){
  const int wg = blockIdx.x;
  const int cpair = wg & 127;
  const int sig = wg >> 7;
  const int c0 = cpair*2;
  const int t = threadIdx.x;
  __shared__ float re[2][264], im[2][264];
#pragma unroll
  for (int i = 0; i < 2; i++){
    const int li = t + i*256;
    const int cc = li >> 8, m = li & 255;
    const int c = c0 + cc;
    float vx = 0.0f, vy = 0.0f;
    if (m < 128){                       // n = c + 256*m < 32768
      if (mode == 0){
        const int rr = sig >> 1, pq = sig & 1;
        const int ch0 = rr*4 + pq*2;
        vx = w_resT[(size_t)ch0*32768 + c*128 + m] * w_invnorm[ch0];
        vy = w_resT[(size_t)(ch0+1)*32768 + c*128 + m] * w_invnorm[ch0+1];
      } else {
        const int n = c + 256*m;
        int lo, hi; float w;
        interp128(n, lo, hi, w);
        const float* rp = w_routed + sig*128;
        float rv = rp[lo]*(1.0f - w) + rp[hi]*w;
        vx = rv * jax_noise((uint32_t)sig*32768u + (uint32_t)n);
      }
    }
    re[cc][SK(m)] = vx; im[cc][SK(m)] = vy;
  }
  __syncthreads();
  const int arr = t >> 7, b = t & 127;
  for (int s = 0; s < 8; s++){
    const int ls = 7 - s;
    const int hl = 1 << ls;
    const int g = b >> ls, j = b & (hl - 1);
    const int i0 = g*2*hl + j, i1 = i0 + hl;
    float2 u = make_float2(re[arr][SK(i0)], im[arr][SK(i0)]);
    float2 v = make_float2(re[arr][SK(i1)], im[arr][SK(i1)]);
    uint32_t e = (((uint32_t)(c0 + arr) + 256u*(uint32_t)j) << s) & 0xFFFFu;
    float2 w = twid(e, UNIT64K, -1.0f);
    re[arr][SK(i0)] = u.x + v.x; im[arr][SK(i0)] = u.y + v.y;
    float2 d = make_float2(u.x - v.x, u.y - v.y);
    float2 dv = cmul(d, w);
    re[arr][SK(i1)] = dv.x; im[arr][SK(i1)] = dv.y;
    __syncthreads();
  }
#pragma unroll
  for (int i = 0; i < 2; i++){
    const int li = t + i*256;
    const int cc = li >> 8, m = li & 255;
    spec[(size_t)sig*65536 + (size_t)(c0+cc)*256 + m] =
        make_float2(re[cc][SK(m)], im[cc][SK(m)]);
  }
}

// ------- forward block stages (s=8..15): 256-pt DIF over c per m, in place --
__global__ void k_fwdB(float2* __restrict__ spec){
  const int wg = blockIdx.x;
  const int mq = wg & 31;
  const int sig = wg >> 5;
  const int m8 = mq*8;
  const int t = threadIdx.x;
  __shared__ float re[8][264], im[8][264];
  float2* base = spec + (size_t)sig*65536;
#pragma unroll
  for (int i = 0; i < 8; i++){
    const int li = t + i*256;          // li = c*8 + mm
    const int mm = li & 7, c = li >> 3;
    float2 v = base[(size_t)c*256 + m8 + mm];
    re[mm][SK(c)] = v.x; im[mm][SK(c)] = v.y;
  }
  __syncthreads();
  for (int s = 8; s < 16; s++){
    const int ls = 15 - s;
    const int hl = 1 << ls;            // 128..1
#pragma unroll
    for (int it = 0; it < 4; it++){
      const int task = t + it*256;
      const int arr = task >> 7, b = task & 127;
      const int g = b >> ls, j = b & (hl - 1);
      const int i0 = g*2*hl + j, i1 = i0 + hl;
      float2 u = make_float2(re[arr][SK(i0)], im[arr][SK(i0)]);
      float2 v = make_float2(re[arr][SK(i1)], im[arr][SK(i1)]);
      float2 w = twid((uint32_t)(j << s), UNIT64K, -1.0f);
      re[arr][SK(i0)] = u.x + v.x; im[arr][SK(i0)] = u.y + v.y;
      float2 d = make_float2(u.x - v.x, u.y - v.y);
      float2 dv = cmul(d, w);
      re[arr][SK(i1)] = dv.x; im[arr][SK(i1)] = dv.y;
    }
    __syncthreads();
  }
#pragma unroll
  for (int i = 0; i < 8; i++){
    const int li = t + i*256;
    const int mm = li & 7, c = li >> 3;
    base[(size_t)c*256 + m8 + mm] = make_float2(re[mm][SK(c)], im[mm][SK(c)]);
  }
}

// -- product + inverse block stages (s=15..8): per packed combo q, 8-m slab --
// chunk n-major: CH[q][m*256 + c]
__global__ void k_prod_invB(const float2* __restrict__ ruspec,
                            const float2* __restrict__ respspec,
                            float2* __restrict__ chunkbuf, const int gbase){
  const int wg = blockIdx.x;
  const int mq = wg & 31;
  const int q = wg >> 5;               // local packed combo: (gl, p)
  const int g = gbase + (q >> 1), p = q & 1;
  const int r = g & 31;
  const int rp = r*2 + p;
  const int m8 = mq*8;
  const int t = threadIdx.x;
  __shared__ float re[8][264], im[8][264];
  const float2* A = ruspec + (size_t)g*65536;
  const float2* B = respspec + (size_t)rp*65536;
#pragma unroll
  for (int i = 0; i < 8; i++){
    const int li = t + i*256;          // li = c*8 + mm
    const int mm = li & 7, c = li >> 3;
    const size_t a = (size_t)c*256 + m8 + mm;
    float2 v = cmul(A[a], B[a]);
    re[mm][SK(c)] = v.x; im[mm][SK(c)] = v.y;
  }
  __syncthreads();
  for (int s = 15; s >= 8; s--){
    const int ls = 15 - s;
    const int hl = 1 << ls;            // 1..128
#pragma unroll
    for (int it = 0; it < 4; it++){
      const int task = t + it*256;
      const int arr = task >> 7, b = task & 127;
      const int g2 = b >> ls, j = b & (hl - 1);
      const int i0 = g2*2*hl + j, i1 = i0 + hl;
      float2 pp = make_float2(re[arr][SK(i0)], im[arr][SK(i0)]);
      float2 qq = make_float2(re[arr][SK(i1)], im[arr][SK(i1)]);
      float2 w = twid((uint32_t)(j << s), UNIT64K, +1.0f);
      float2 v = cmul(qq, w);
      re[arr][SK(i0)] = pp.x + v.x; im[arr][SK(i0)] = pp.y + v.y;
      re[arr][SK(i1)] = pp.x - v.x; im[arr][SK(i1)] = pp.y - v.y;
    }
    __syncthreads();
  }
  float2* O = chunkbuf + (size_t)q*65536;
#pragma unroll
  for (int i = 0; i < 8; i++){
    const int li = t + i*256;          // li = mm*256 + c -> contiguous rows
    const int mm = li >> 8, c = li & 255;
    O[(size_t)(m8+mm)*256 + c] = make_float2(re[mm][SK(c)], im[mm][SK(c)]);
  }
}

// -- inverse comb stages (s=7..0): 8 combs x 2 p per block, fused epilogue --
__global__ void k_invA_w(const float2* __restrict__ chunkbuf, const int gbase,
                         const float* __restrict__ w_sm, const float* __restrict__ gains,
                         float* __restrict__ out0){
  const int wg = blockIdx.x;
  const int c8 = wg & 31;
  const int gl = wg >> 5;
  const int g = gbase + gl;
  const int r = g & 31, be = g >> 5;
  const int c0 = c8*8;
  const int t = threadIdx.x;
  __shared__ float re[2][8][264], im[2][8][264];
#pragma unroll
  for (int p = 0; p < 2; p++){
    const float2* C = chunkbuf + (size_t)(gl*2 + p)*65536;
#pragma unroll
    for (int i = 0; i < 8; i++){
      const int li = t + i*256;        // li = m*8 + cc -> 64B clusters
      const int cc = li & 7, m = li >> 3;
      float2 v = C[(size_t)m*256 + c0 + cc];
      re[p][cc][SK(m)] = v.x; im[p][cc][SK(m)] = v.y;
    }
  }
  __syncthreads();
  for (int s = 7; s >= 0; s--){
    const int ls = 7 - s;
    const int hl = 1 << ls;            // 1..128
#pragma unroll
    for (int it = 0; it < 8; it++){
      const int task = t + it*256;     // p(1) cc(3) b(7)
      const int b = task & 127;
      const int cc = (task >> 7) & 7;
      const int p = task >> 10;
      const int g2 = b >> ls, j = b & (hl - 1);
      const int i0 = g2*2*hl + j, i1 = i0 + hl;
      float2 pp = make_float2(re[p][cc][SK(i0)], im[p][cc][SK(i0)]);
      float2 qq = make_float2(re[p][cc][SK(i1)], im[p][cc][SK(i1)]);
      uint32_t e = (((uint32_t)(c0 + cc) + 256u*(uint32_t)j) << s) & 0xFFFFu;
      float2 w = twid(e, UNIT64K, +1.0f);
      float2 v = cmul(qq, w);
      re[p][cc][SK(i0)] = pp.x + v.x; im[p][cc][SK(i0)] = pp.y + v.y;
      re[p][cc][SK(i1)] = pp.x - v.x; im[p][cc][SK(i1)] = pp.y - v.y;
    }
    __syncthreads();
  }
  const float gv = fabsf(gains[r]);
  const float* smb = w_sm + be*512;
#pragma unroll
  for (int it = 0; it < 4; it++){
    const int li = t + it*256;         // li = m*8 + cc, m < 128
    const int cc = li & 7, m = li >> 3;
    const int tt = c0 + cc + 256*m;
    int lo, hi; float w;
    interp128(tt, lo, hi, w);
    float val = 0.0f;
#pragma unroll
    for (int p = 0; p < 2; p++){
      float z_re = re[p][cc][SK(m)], z_im = im[p][cc][SK(m)];
      float dw0 = smb[(2*p  )*128 + lo]*(1.0f - w) + smb[(2*p  )*128 + hi]*w;
      float dw1 = smb[(2*p+1)*128 + lo]*(1.0f - w) + smb[(2*p+1)*128 + hi]*w;
      val += dw0*z_re + dw1*z_im;
    }
    val *= (1.0f/65536.0f);
    atomicAdd(&out0[(size_t)be*32768 + tt], tanhf(val*gv));
  }
}

extern "C" void kernel_launch(void* const* d_in, const int* in_sizes, int n_in,
                              void* d_out, int out_size, void* d_ws, size_t ws_size,
                              hipStream_t stream){
  const float* ctrl   = (const float*)d_in[0];
  const float* defm   = (const float*)d_in[1];
  const float* router = (const float*)d_in[2];
  const float* amp    = (const float*)d_in[3];
  const float* phase  = (const float*)d_in[4];
  const float* decay  = (const float*)d_in[5];
  const float* gains  = (const float*)d_in[6];
  float* out = (float*)d_out;
  float* ws  = (float*)d_ws;

  // ws layout (float offsets)
  float*  w_resT    = ws;                         // 128*32768      = 4,194,304
  float*  w_routed  = ws + 4194304;               // 32768
  float*  w_sm      = ws + 4227072;               // 4096
  float*  w_invnorm = ws + 4231168;               // 128
  float*  w_sumsq   = ws + 4231296;               // 128
  float2* w_ruspec  = (float2*)(ws + 4231424);    // 256*65536 c    = 33,554,432 f
  float2* w_resp    = (float2*)(ws + 37785856);   // 64*65536 c     = 8,388,608 f
  float2* w_chunk   = (float2*)(ws + 46174464);   // 2G*65536 c
  const size_t base_f = 46174464;
  // frames scratch aliases the ruspec region (ruspec written later by fwdA)
  float2* w_fr      = w_ruspec;                   // 2048*2048 c = 8,388,608 f

  int G = 0;
  for (int gg = 64; gg >= 1; gg >>= 1){
    size_t need = (base_f + (size_t)gg*262144) * sizeof(float);
    if (need <= ws_size){ G = gg; break; }
  }

  hipMemsetAsync(d_out, 0, 262144*sizeof(float), stream);  // out0 (atomicAdd)
  k_routed<<<132, 256, 0, stream>>>(ctrl, defm, router, w_routed, w_sm, out + 262144);
  if (G == 0) return;  // diagnostic: out1 ok, out0 stays 0 => ws too small

  hipMemsetAsync(w_sumsq, 0, 128*sizeof(float), stream);
  k_frames<<<2048, 256, 0, stream>>>(amp, phase, decay, w_fr);
  k_ola<<<512, 256, 0, stream>>>(w_fr, w_resT, w_sumsq);
  k_norm<<<1, 128, 0, stream>>>(w_sumsq, w_invnorm);
  k_fwdA<<<64*128, 256, 0, stream>>>(0, w_resT, w_invnorm, w_routed, w_resp);
  k_fwdB<<<64*32, 256, 0, stream>>>(w_resp);
  k_fwdA<<<256*128, 256, 0, stream>>>(1, w_resT, w_invnorm, w_routed, w_ruspec);
  k_fwdB<<<256*32, 256, 0, stream>>>(w_ruspec);
  for (int gb = 0; gb < 256; gb += G){
    k_prod_invB<<<G*2*32, 256, 0, stream>>>(w_ruspec, w_resp, w_chunk, gb);
    k_invA_w<<<G*32, 256, 0, stream>>>(w_chunk, gb, w_sm, gains, out);
  }
}